// Round 16
// baseline (197.136 us; speedup 1.0000x reference)
//
#include <hip/hip_runtime.h>

typedef unsigned short u16;
typedef __attribute__((ext_vector_type(8))) short bf16x8;
typedef __attribute__((ext_vector_type(4))) float f32x4;

#define HID 2048
#define NH 16
#define QLR 1536
#define KVLR 512
#define DR 64
#define DN 128
#define DQK 192
#define DV 128
#define SEQ 2048
#define NKVA 2176
#define SCALE 0.07216878364870323f           // 192^-0.5
#define SCL2 0.1041164359699839f             // SCALE * log2(e) -> exp2 domain
#define THR2 11.541560327111707f             // 8 * log2(e)

static __device__ __forceinline__ u16 f2bf(float f) {
  unsigned v = __builtin_bit_cast(unsigned, f);
  v = v + 0x7fffu + ((v >> 16) & 1u);
  return (u16)(v >> 16);
}
static __device__ __forceinline__ float bf2f(u16 u) {
  unsigned v = ((unsigned)u) << 16;
  return __builtin_bit_cast(float, v);
}

#define GLOAD16(gp, lp)                                                        \
  __builtin_amdgcn_global_load_lds(                                            \
      (const __attribute__((address_space(1))) void*)(gp),                     \
      (__attribute__((address_space(3))) void*)(lp), 16, 0, 0)

// ------------- fused f32->bf16 convert for all 5 weight/act buffers ---------
__global__ void k_convert_all(const float* __restrict__ hs, const float* __restrict__ wq_a,
                              const float* __restrict__ wkv_a, const float* __restrict__ wqb,
                              const float* __restrict__ wkvb, const float* __restrict__ wo,
                              u16* __restrict__ hs_bf, u16* __restrict__ wqkva,
                              u16* __restrict__ wqb_bf, u16* __restrict__ wkvb_bf,
                              u16* __restrict__ wo_bf) {
  const long NQ = 4915200;
  long q = (long)blockIdx.x * blockDim.x + threadIdx.x;
  const long stride = (long)gridDim.x * blockDim.x;
  for (; q < NQ; q += stride) {
    const float* src;
    u16* dst;
    long li;
    bool zero = false;
    if (q < 1048576)        { src = hs;   dst = hs_bf;                      li = q; }
    else if (q < 1835008)   { src = wq_a; dst = wqkva;                      li = q - 1048576; }
    else if (q < 2162688)   { li = q - 1835008; src = wkv_a; dst = wqkva + (size_t)QLR * HID;
                              zero = (li >= 294912); }
    else if (q < 3342336)   { src = wqb;  dst = wqb_bf;                     li = q - 2162688; }
    else if (q < 3866624)   { src = wkvb; dst = wkvb_bf;                    li = q - 3342336; }
    else                    { src = wo;   dst = wo_bf;                      li = q - 3866624; }
    u16 o0 = 0, o1 = 0, o2 = 0, o3 = 0;
    if (!zero) {
      const float4 f = *(const float4*)(src + li * 4);
      o0 = f2bf(f.x); o1 = f2bf(f.y); o2 = f2bf(f.z); o3 = f2bf(f.w);
    }
    u16* d = dst + li * 4;
    d[0] = o0; d[1] = o1; d[2] = o2; d[3] = o3;
  }
}

// ---------------- fused row RMSNorm (y-dim selects q / kv config) ----------
__global__ void k_rmsnorm2(const float* __restrict__ qkva, const float* __restrict__ qw,
                           const float* __restrict__ kvw, u16* __restrict__ q_ln,
                           u16* __restrict__ kv_ln) {
  const int row = blockIdx.x;
  const int which = blockIdx.y;
  const int t = threadIdx.x;
  const int cols = which ? KVLR : QLR;
  const float inv_cols = which ? (1.0f / KVLR) : (1.0f / QLR);
  const float* x = qkva + (size_t)row * NKVA + (which ? QLR : 0);
  const float* w = which ? kvw : qw;
  u16* Y = (which ? kv_ln : q_ln) + (size_t)row * cols;
  float ss = 0.f;
  for (int i = t * 4; i < cols; i += 1024) {
    float4 v = *(const float4*)(x + i);
    ss += v.x * v.x + v.y * v.y + v.z * v.z + v.w * v.w;
  }
#pragma unroll
  for (int m = 1; m < 64; m <<= 1) ss += __shfl_xor(ss, m, 64);
  __shared__ float red[4];
  if ((t & 63) == 0) red[t >> 6] = ss;
  __syncthreads();
  float tot = red[0] + red[1] + red[2] + red[3];
  float r = rsqrtf(tot * inv_cols + 1e-6f);
  for (int i = t * 4; i < cols; i += 1024) {
    float4 v = *(const float4*)(x + i);
    float4 g = *(const float4*)(w + i);
    u16* y = Y + i;
    y[0] = f2bf(v.x * r * g.x);
    y[1] = f2bf(v.y * r * g.y);
    y[2] = f2bf(v.z * r * g.z);
    y[3] = f2bf(v.w * r * g.w);
  }
}

// ------------- NT GEMM 8-wave wide tile, NBUF-deep counted-vmcnt ------------
// BM=128, BN=WN*64; waves 2(row)x4(col).
// MODE 0: f32 store   MODE 1: bf16 store
// MODE 2 (WN=3): qf epilogue — head h=bn, pass cols *SCL2, rope cols rotated.
// MODE 3 (WN=4): kv epilogue — kf pass cols direct, v via LDS transpose -> vt.
template <int WN, int NBUF, int MODE>
__global__ __launch_bounds__(512) void k_gemm_nt8(
    const u16* __restrict__ A, const u16* __restrict__ B, void* __restrict__ Cout,
    int M, int N, int K, const float* __restrict__ cosb, const float* __restrict__ sinb,
    u16* __restrict__ out_a, u16* __restrict__ out_b) {
  constexpr int BN = WN * 64;
  constexpr int NST = 2 + WN;  // gload instrs per STAGE8
  __shared__ __align__(16) u16 As[NBUF][128 * 64];
  __shared__ __align__(16) u16 Bs[NBUF][BN * 64];
  __shared__ __align__(16) u16 vts[MODE == 3 ? 128 * 130 : 2];
  const int t = threadIdx.x;
  const int lane = t & 63;
  const int w = t >> 6, wr = w >> 2, wc = w & 3;
  const int lm = lane & 15, lg = lane >> 4;

  const int nwg = gridDim.x * gridDim.y;
  int bid = blockIdx.y * gridDim.x + blockIdx.x;
  if ((nwg & 7) == 0) bid = (bid & 7) * (nwg >> 3) + (bid >> 3);
  const int bm = bid % gridDim.y;
  const int bn = bid / gridDim.y;

  const u16* aT = A + (size_t)bm * 128 * K;
  const u16* bT = B + (size_t)bn * BN * K;

#define STAGE8(buf, kt_)                                                       \
  do {                                                                         \
    _Pragma("unroll") for (int i = 0; i < 2; ++i) {                            \
      const int g = t + i * 512, row = g >> 3, slot = (g & 7) ^ (row & 7);     \
      GLOAD16(aT + (size_t)row * K + slot * 8 + (kt_), (u16*)As[buf] + g * 8); \
    }                                                                          \
    _Pragma("unroll") for (int i = 0; i < WN; ++i) {                           \
      const int g = t + i * 512, row = g >> 3, slot = (g & 7) ^ (row & 7);     \
      GLOAD16(bT + (size_t)row * K + slot * 8 + (kt_), (u16*)Bs[buf] + g * 8); \
    }                                                                          \
  } while (0)

  f32x4 acc[4][WN] = {};
  const int nk = K >> 6;
#pragma unroll
  for (int b = 0; b < NBUF; ++b)
    if (b < nk) STAGE8(b, b << 6);
  int bt = 0;
  for (int kt = 0; kt < nk; ++kt) {
    const int rem = nk - 1 - kt;
    if constexpr (NBUF == 3) {
      if (rem >= 2)      asm volatile("s_waitcnt vmcnt(%0)" :: "i"(2 * NST) : "memory");
      else if (rem == 1) asm volatile("s_waitcnt vmcnt(%0)" :: "i"(NST) : "memory");
      else               asm volatile("s_waitcnt vmcnt(0)" ::: "memory");
    } else {
      if (rem >= 1)      asm volatile("s_waitcnt vmcnt(%0)" :: "i"(NST) : "memory");
      else               asm volatile("s_waitcnt vmcnt(0)" ::: "memory");
    }
    __builtin_amdgcn_s_barrier();
    __builtin_amdgcn_sched_barrier(0);
    bf16x8 af[2][4], bfr[2][WN];
#pragma unroll
    for (int kk = 0; kk < 2; ++kk) {
#pragma unroll
      for (int i = 0; i < 4; ++i) {
        const int row_ = wr * 64 + i * 16 + lm;
        af[kk][i] = *(const bf16x8*)(As[bt] + row_ * 64 +
                                     ((((kk << 2) | lg) ^ (row_ & 7)) << 3));
      }
#pragma unroll
      for (int j = 0; j < WN; ++j) {
        const int row_ = wc * (WN * 16) + j * 16 + lm;
        bfr[kk][j] = *(const bf16x8*)(Bs[bt] + row_ * 64 +
                                      ((((kk << 2) | lg) ^ (row_ & 7)) << 3));
      }
    }
    asm volatile("s_waitcnt lgkmcnt(0)" ::: "memory");
    __builtin_amdgcn_sched_barrier(0);
    __builtin_amdgcn_s_barrier();
    __builtin_amdgcn_sched_barrier(0);
    if (kt + NBUF < nk) STAGE8(bt, (kt + NBUF) << 6);  // same buf (mod NBUF)
    __builtin_amdgcn_s_setprio(1);
#pragma unroll
    for (int kk = 0; kk < 2; ++kk)
#pragma unroll
      for (int i = 0; i < 4; ++i)
#pragma unroll
        for (int j = 0; j < WN; ++j)
          acc[i][j] = __builtin_amdgcn_mfma_f32_16x16x32_bf16(af[kk][i], bfr[kk][j],
                                                              acc[i][j], 0, 0, 0);
    __builtin_amdgcn_s_setprio(0);
    bt = (bt == NBUF - 1) ? 0 : bt + 1;
  }
#undef STAGE8

  const int row0 = bm * 128 + wr * 64 + lg * 4;
  const int col0 = bn * BN + wc * (WN * 16) + lm;
  if constexpr (MODE == 1) {
    u16* C = (u16*)Cout;
#pragma unroll
    for (int i = 0; i < 4; ++i)
#pragma unroll
      for (int r = 0; r < 4; ++r) {
        u16* crow = C + (size_t)(row0 + i * 16 + r) * N + col0;
#pragma unroll
        for (int j = 0; j < WN; ++j) crow[j * 16] = f2bf(acc[i][j][r]);
      }
  } else if constexpr (MODE == 0) {
    float* C = (float*)Cout;
#pragma unroll
    for (int i = 0; i < 4; ++i)
#pragma unroll
      for (int r = 0; r < 4; ++r) {
        float* crow = C + (size_t)(row0 + i * 16 + r) * N + col0;
#pragma unroll
        for (int j = 0; j < WN; ++j) crow[j * 16] = acc[i][j][r];
      }
  } else if constexpr (MODE == 2) {
    const int h = bn;
#pragma unroll
    for (int i = 0; i < 4; ++i)
#pragma unroll
      for (int r = 0; r < 4; ++r) {
        const int s = row0 + i * 16 + r;
        u16* qrow = out_a + ((size_t)h * SEQ + s) * DQK;
#pragma unroll
        for (int j = 0; j < WN; ++j) {
          const int c = wc * 48 + j * 16 + lm;
          float val = acc[i][j][r];
          float partner = __shfl_xor(val, 1, 64);
          if (c < 128) {
            qrow[c] = f2bf(val * SCL2);
          } else {
            const int u = c - 128, p = u >> 1, od = u & 1;
            float cv = cosb[(size_t)s * DR + p];
            float sv = sinb[(size_t)s * DR + p];
            float o = od ? (val * cv + partner * sv) : (val * cv - partner * sv);
            qrow[128 + od * 32 + p] = f2bf(o * SCL2);
          }
        }
      }
  } else {
    const int h = bn;
    const int sl0 = wr * 64 + lg * 4;
#pragma unroll
    for (int i = 0; i < 4; ++i)
#pragma unroll
      for (int r = 0; r < 4; ++r) {
        const int s = row0 + i * 16 + r;
        const int sl = sl0 + i * 16 + r;
#pragma unroll
        for (int j = 0; j < WN; ++j) {
          const int c = wc * 64 + j * 16 + lm;
          const u16 bv = f2bf(acc[i][j][r]);
          if (c < 128) out_a[((size_t)h * SEQ + s) * DQK + c] = bv;
          else vts[(c - 128) * 130 + sl] = bv;
        }
      }
    __syncthreads();
    const int d = t >> 2, q4 = t & 3;
#pragma unroll
    for (int sub = 0; sub < 4; ++sub) {
      bf16x8 v;
#pragma unroll
      for (int e = 0; e < 8; ++e) v[e] = (short)vts[d * 130 + q4 * 32 + sub * 8 + e];
      *(bf16x8*)(out_b + ((size_t)h * DV + d) * SEQ + bm * 128 + q4 * 32 + sub * 8) = v;
    }
  }
}

// ------- kf rope cols (128..192): shared k_rot, broadcast to all heads ------
__global__ __launch_bounds__(256) void k_rope_k(
    const float* __restrict__ krot, int stride, const float* __restrict__ cosb,
    const float* __restrict__ sinb, u16* __restrict__ kf) {
  const int s0 = blockIdx.x * 32;
  const int t = threadIdx.x;
  const int row = t >> 3, c8 = t & 7;
  const int s = s0 + row;
  const int half = c8 >> 2, p0 = (c8 & 3) * 8;
  bf16x8 v;
#pragma unroll
  for (int e = 0; e < 8; ++e) {
    const int p = p0 + e;
    float a = krot[(size_t)s * stride + 2 * p];
    float b = krot[(size_t)s * stride + 2 * p + 1];
    float cv = cosb[(size_t)s * DR + p];
    float sv = sinb[(size_t)s * DR + p];
    v[e] = (short)f2bf(half ? (b * cv + a * sv) : (a * cv - b * sv));
  }
#pragma unroll
  for (int h = 0; h < NH; ++h)
    *(bf16x8*)(kf + ((size_t)h * SEQ + s) * DQK + 128 + half * 32 + p0) = v;
}

// ---------------- flash attention v11: KVBLK=64, V direct from L2 -----------
// One barrier pair per 64 kv (two 32-kv compute subs); K LDS-staged 2-buffer
// (6 gloads/stage, counted vmcnt(6)); V loaded straight to regs (L2-resident).
// Task = (head, 64-row tile, chunk of <=8 64-kv steps), 768 blocks, 3/CU.
__global__ __launch_bounds__(256) void k_attn(
    const u16* __restrict__ qf, const u16* __restrict__ kf, const u16* __restrict__ vt,
    u16* __restrict__ attn_out, float* __restrict__ O_part, float* __restrict__ mlbuf) {
  __shared__ __align__(16) u16 Ks[2][64 * 192];
  __shared__ __align__(16) u16 p_lds[4][16][32];

  // slots sorted desc by step count (64-kv units): split tiles tj>=8 at
  // h0=ceil((tj+1)/2); whole tiles tj<8.
  static const signed char TJ[24] = {15,15,14,7, 14,13,13,12,6, 12,11,11,10,5,
                                     10,9,9,8,4, 8,3, 2, 1, 0};
  static const signed char CK[24] = {0,1,0,2, 1,0,1,0,2, 1,0,1,0,2,
                                     1,0,1,0,2, 1,2, 2, 2, 2};

  const int t = threadIdx.x, lane = t & 63, w = t >> 6;
  const int lm = lane & 15, lg = lane >> 4;
  const int bid = blockIdx.x;
  const int x = bid & 7, rr = bid >> 3;   // rr in [0,96)
  const int hh = rr & 1, idx = rr >> 1;   // idx in [0,48)
  const int seg = idx & 1, slot = idx >> 1;
  const int tj = TJ[slot], ck = CK[slot];
  const int h = x * 2 + hh;               // 2 heads per XCD
  const int tile_row0 = seg * 1024 + tj * 64;
  const int k_begin = seg * 1024;
  const int h0 = (tj + 2) >> 1;           // split boundary (64-kv units)
  const int u_lo = (ck == 1) ? h0 : 0;
  const int u_hi = (ck == 0) ? h0 : (tj + 1);
  const int nst = u_hi - u_lo;            // 1..8

  const int lo_row = tile_row0 + w * 16;
  bf16x8 qfr[6];
  {
    const u16* qp = qf + ((size_t)h * SEQ + (lo_row + lm)) * DQK + lg * 8;
#pragma unroll
    for (int c = 0; c < 6; ++c) qfr[c] = *(const bf16x8*)(qp + c * 32);
  }
  int qrow[4];
#pragma unroll
  for (int r = 0; r < 4; ++r) qrow[r] = lo_row + lg * 4 + r;

  float m_r[4], l_loc[4];
#pragma unroll
  for (int r = 0; r < 4; ++r) { m_r[r] = -3.0e4f; l_loc[r] = 0.f; }
  f32x4 oacc[8] = {};
  bf16x8 pa, vv[8];

#define STAGEA(buf, u_)                                                        \
  do {                                                                         \
    const int k0_ = k_begin + (u_) * 64;                                       \
    _Pragma("unroll") for (int p = 0; p < 6; ++p) {                            \
      const int id = p * 256 + t;                                              \
      const int row = id / 24, colL = id - row * 24;                           \
      const u16* g = kf + ((size_t)h * SEQ + k0_ + row) * DQK +                \
                     ((colL ^ (row & 7)) * 8);                                 \
      GLOAD16(g, (u16*)Ks[buf] + id * 8);                                      \
    }                                                                          \
  } while (0)

// QK (K from LDS sub-tile) + direct V loads + softmax + pa read
#define COMPUTE1(buf, sub, k0_)                                                \
  do {                                                                         \
    f32x4 sc[2] = {};                                                          \
    __builtin_amdgcn_s_setprio(1);                                             \
    _Pragma("unroll") for (int n0_ = 0; n0_ < 2; ++n0_)                        \
        _Pragma("unroll") for (int c_ = 0; c_ < 6; ++c_) {                     \
      const int row_ = n0_ * 16 + lm, cc_ = c_ * 4 + lg;                       \
      bf16x8 kfr = *(const bf16x8*)(Ks[buf] + ((sub) * 32 + row_) * 192 +      \
                                    ((cc_ ^ (row_ & 7)) * 8));                 \
      sc[n0_] = __builtin_amdgcn_mfma_f32_16x16x32_bf16(qfr[c_], kfr,          \
                                                        sc[n0_], 0, 0, 0);     \
    }                                                                          \
    __builtin_amdgcn_s_setprio(0);                                             \
    _Pragma("unroll") for (int nd = 0; nd < 8; ++nd) {                         \
      vv[nd] = *(const bf16x8*)(vt + ((size_t)h * DV + nd * 16 + lm) * SEQ +   \
                                (k0_) + lg * 8);                               \
    }                                                                          \
    float s0a[4], s1a[4];                                                      \
    float over = -1e30f;                                                       \
    if (lo_row >= (k0_) + 31) {                                                \
      _Pragma("unroll") for (int r = 0; r < 4; ++r) {                          \
        s0a[r] = sc[0][r];                                                     \
        s1a[r] = sc[1][r];                                                     \
        over = fmaxf(over, fmaxf(s0a[r], s1a[r]) - m_r[r]);                    \
      }                                                                        \
    } else {                                                                   \
      const int kc0 = (k0_) + lm, kc1 = (k0_) + 16 + lm;                       \
      _Pragma("unroll") for (int r = 0; r < 4; ++r) {                          \
        s0a[r] = (kc0 <= qrow[r]) ? sc[0][r] : -1e30f;                         \
        s1a[r] = (kc1 <= qrow[r]) ? sc[1][r] : -1e30f;                         \
        over = fmaxf(over, fmaxf(s0a[r], s1a[r]) - m_r[r]);                    \
      }                                                                        \
    }                                                                          \
    if (__any(over > THR2)) {                                                  \
      _Pragma("unroll") for (int r = 0; r < 4; ++r) {                          \
        float mx = fmaxf(s0a[r], s1a[r]);                                      \
        _Pragma("unroll") for (int md = 1; md < 16; md <<= 1)                  \
            mx = fmaxf(mx, __shfl_xor(mx, md, 64));                            \
        float mnew = fmaxf(m_r[r], mx);                                        \
        float alpha = exp2f(m_r[r] - mnew);                                    \
        m_r[r] = mnew;                                                         \
        l_loc[r] *= alpha;                                                     \
        _Pragma("unroll") for (int nd = 0; nd < 8; ++nd) oacc[nd][r] *= alpha; \
      }                                                                        \
    }                                                                          \
    _Pragma("unroll") for (int r = 0; r < 4; ++r) {                            \
      float p0 = exp2f(s0a[r] - m_r[r]);                                       \
      float p1 = exp2f(s1a[r] - m_r[r]);                                       \
      l_loc[r] += p0 + p1;                                                     \
      p_lds[w][lg * 4 + r][lm] = f2bf(p0);                                     \
      p_lds[w][lg * 4 + r][16 + lm] = f2bf(p1);                                \
    }                                                                          \
    asm volatile("s_waitcnt lgkmcnt(0)" ::: "memory");                         \
    __builtin_amdgcn_sched_barrier(0);                                         \
    pa = *(const bf16x8*)(&p_lds[w][lm][lg * 8]);                              \
  } while (0)

#define PVSTEP                                                                 \
  do {                                                                         \
    __builtin_amdgcn_s_setprio(1);                                             \
    _Pragma("unroll") for (int nd = 0; nd < 8; ++nd)                           \
        oacc[nd] =                                                             \
        __builtin_amdgcn_mfma_f32_16x16x32_bf16(pa, vv[nd], oacc[nd], 0, 0, 0);\
    __builtin_amdgcn_s_setprio(0);                                             \
  } while (0)

  STAGEA(0, u_lo);
  if (nst > 1) STAGEA(1, u_lo + 1);
  int bt = 0;
  for (int i = 0; i < nst; ++i) {
    const int u = u_lo + i;
    if (i + 1 < nst) asm volatile("s_waitcnt vmcnt(6)" ::: "memory");
    else             asm volatile("s_waitcnt vmcnt(0)" ::: "memory");
    __builtin_amdgcn_s_barrier();
    __builtin_amdgcn_sched_barrier(0);
    COMPUTE1(bt, 0, k_begin + u * 64);
    PVSTEP;
    COMPUTE1(bt, 1, k_begin + u * 64 + 32);
    asm volatile("s_waitcnt lgkmcnt(0)" ::: "memory");
    __builtin_amdgcn_sched_barrier(0);
    __builtin_amdgcn_s_barrier();
    __builtin_amdgcn_sched_barrier(0);
    if (i + 2 < nst) STAGEA(bt, u + 2);
    PVSTEP;  // PV of sub1 overlaps next stage
    bt ^= 1;
  }
#undef STAGEA
#undef COMPUTE1
#undef PVSTEP

  float l_row[4];
#pragma unroll
  for (int r = 0; r < 4; ++r) {
    float lt = l_loc[r];
#pragma unroll
    for (int md = 1; md < 16; md <<= 1) lt += __shfl_xor(lt, md, 64);
    l_row[r] = lt;
  }

  if (ck == 2) {
#pragma unroll
    for (int r = 0; r < 4; ++r) {
      float inv = 1.0f / l_row[r];
#pragma unroll
      for (int nd = 0; nd < 8; ++nd)
        attn_out[(size_t)qrow[r] * (NH * DV) + h * DV + nd * 16 + lm] =
            f2bf(oacc[nd][r] * inv);
    }
  } else {
    const int part = (((tj - 8) * 2 + seg) * 16 + h) * 2 + ck;  // [0,512)
    float* op = O_part + (size_t)part * 8192;
#pragma unroll
    for (int r = 0; r < 4; ++r) {
      const int rw = w * 16 + lg * 4 + r;  // [0,64)
#pragma unroll
      for (int nd = 0; nd < 8; ++nd)
        op[rw * 128 + nd * 16 + lm] = oacc[nd][r];
      if (lm == 0) {
        mlbuf[part * 128 + rw] = m_r[r];
        mlbuf[part * 128 + 64 + rw] = l_row[r];
      }
    }
  }
}

// ---------------- merge 2 chunks per split tile -----------------------------
__global__ __launch_bounds__(256) void k_merge(const float* __restrict__ O_part,
                                               const float* __restrict__ mlbuf,
                                               u16* __restrict__ attn_out) {
  const int b = blockIdx.x;            // [0,256)
  const int h = b & 15, z = b >> 4;    // z in [0,16)
  const int tj = 8 + (z >> 1), seg = z & 1;
  const int p0 = (((tj - 8) * 2 + seg) * 16 + h) * 2;
  const int p1 = p0 + 1;
  const int t = threadIdx.x;
  const int row = t >> 2, cg = t & 3;

  const float m0 = mlbuf[p0 * 128 + row], l0 = mlbuf[p0 * 128 + 64 + row];
  const float m1 = mlbuf[p1 * 128 + row], l1 = mlbuf[p1 * 128 + 64 + row];
  const float M = fmaxf(m0, m1);
  const float w0 = exp2f(m0 - M), w1 = exp2f(m1 - M);
  const float inv = 1.0f / (w0 * l0 + w1 * l1);
  const float a0 = w0 * inv, a1 = w1 * inv;

  const int qrow = seg * 1024 + tj * 64 + row;
  const float* o0 = O_part + (size_t)p0 * 8192 + row * 128 + cg * 32;
  const float* o1 = O_part + (size_t)p1 * 8192 + row * 128 + cg * 32;
  u16* dst = attn_out + (size_t)qrow * (NH * DV) + h * DV + cg * 32;
#pragma unroll
  for (int e = 0; e < 32; e += 4) {
    const float4 u = *(const float4*)(o0 + e);
    const float4 v = *(const float4*)(o1 + e);
    dst[e]     = f2bf(a0 * u.x + a1 * v.x);
    dst[e + 1] = f2bf(a0 * u.y + a1 * v.y);
    dst[e + 2] = f2bf(a0 * u.z + a1 * v.z);
    dst[e + 3] = f2bf(a0 * u.w + a1 * v.w);
  }
}

extern "C" void kernel_launch(void* const* d_in, const int* in_sizes, int n_in,
                              void* d_out, int out_size, void* d_ws, size_t ws_size,
                              hipStream_t stream) {
  const float* hs = (const float*)d_in[0];
  const float* cosb = (const float*)d_in[1];
  const float* sinb = (const float*)d_in[2];
  const float* wq_a = (const float*)d_in[3];
  const float* q_a_ln_w = (const float*)d_in[4];
  const float* wq_b = (const float*)d_in[5];
  const float* wkv_a = (const float*)d_in[6];
  const float* kv_a_ln_w = (const float*)d_in[7];
  const float* wkv_b = (const float*)d_in[8];
  const float* wo = (const float*)d_in[9];

  char* ws = (char*)d_ws;
  size_t off = 0;
  auto take = [&](size_t bytes) {
    size_t o = off;
    off += (bytes + 255) & ~(size_t)255;
    return o;
  };
  u16* hs_bf = (u16*)(ws + take((size_t)SEQ * HID * 2));
  u16* wqkva = (u16*)(ws + take((size_t)NKVA * HID * 2));
  u16* wqb = (u16*)(ws + take((size_t)(NH * DQK) * QLR * 2));
  u16* wkvb = (u16*)(ws + take((size_t)(NH * 256) * KVLR * 2));
  u16* wo_bf = (u16*)(ws + take((size_t)HID * (NH * DV) * 2));
  float* qkva = (float*)(ws + take((size_t)SEQ * NKVA * 4));
  u16* q_ln = (u16*)(ws + take((size_t)SEQ * QLR * 2));
  u16* kv_ln = (u16*)(ws + take((size_t)SEQ * KVLR * 2));
  u16* qf = (u16*)(ws + take((size_t)NH * SEQ * DQK * 2));
  u16* kf = (u16*)(ws + take((size_t)NH * SEQ * DQK * 2));
  u16* vt = (u16*)(ws + take((size_t)NH * DV * SEQ * 2));
  u16* attn = (u16*)(ws + take((size_t)SEQ * NH * DV * 2));
  float* O_part = (float*)(ws + take((size_t)512 * 8192 * 4));
  float* mlbuf = (float*)(ws + take((size_t)512 * 128 * 4));
  if (off > ws_size) return;

  k_convert_all<<<2048, 256, 0, stream>>>(hs, wq_a, wkv_a, wq_b, wkv_b, wo,
                                          hs_bf, wqkva, wqb, wkvb, wo_bf);

  // g1: 8-wave WN=2, 2-buffer, f32 out -> qkva
  dim3 g1(NKVA / 128, SEQ / 128);
  k_gemm_nt8<2, 2, 0><<<g1, 512, 0, stream>>>(hs_bf, wqkva, qkva, SEQ, NKVA, HID,
                                              nullptr, nullptr, nullptr, nullptr);

  k_rmsnorm2<<<dim3(SEQ, 2), 256, 0, stream>>>(qkva, q_a_ln_w, kv_a_ln_w, q_ln, kv_ln);

  // kf rope cols from g1's krot (shared across heads)
  k_rope_k<<<SEQ / 32, 256, 0, stream>>>(qkva + (QLR + KVLR), NKVA, cosb, sinb, kf);

  // g2: qf fused epilogue (head = bn, rope + SCL2)
  dim3 g2(NH * DQK / 192, SEQ / 128);
  k_gemm_nt8<3, 2, 2><<<g2, 512, 0, stream>>>(q_ln, wqb, nullptr, SEQ, NH * DQK, QLR,
                                              cosb, sinb, qf, nullptr);
  // g3: kf/vt fused epilogue (head = bn, LDS transpose for vt)
  dim3 g3(NH * 256 / 256, SEQ / 128);
  k_gemm_nt8<4, 2, 3><<<g3, 512, 0, stream>>>(kv_ln, wkvb, nullptr, SEQ, NH * 256, KVLR,
                                              nullptr, nullptr, kf, vt);

  k_attn<<<768, 256, 0, stream>>>(qf, kf, vt, attn, O_part, mlbuf);
  k_merge<<<256, 256, 0, stream>>>(O_part, mlbuf, attn);

  // g4: 8-wave WN=2, 2-buffer, f32 out -> d_out
  dim3 g4(HID / 128, SEQ / 128);
  k_gemm_nt8<2, 2, 0><<<g4, 512, 0, stream>>>(attn, wo_bf, d_out, SEQ, HID, NH * DV,
                                              nullptr, nullptr, nullptr, nullptr);
}

// Round 17
// 182.793 us; speedup vs baseline: 1.0785x; 1.0785x over previous
//
#include <hip/hip_runtime.h>

typedef unsigned short u16;
typedef __attribute__((ext_vector_type(8))) short bf16x8;
typedef __attribute__((ext_vector_type(4))) float f32x4;

#define HID 2048
#define NH 16
#define QLR 1536
#define KVLR 512
#define DR 64
#define DN 128
#define DQK 192
#define DV 128
#define SEQ 2048
#define NKVA 2176
#define SCALE 0.07216878364870323f           // 192^-0.5
#define SCL2 0.1041164359699839f             // SCALE * log2(e) -> exp2 domain
#define THR2 11.541560327111707f             // 8 * log2(e)

static __device__ __forceinline__ u16 f2bf(float f) {
  unsigned v = __builtin_bit_cast(unsigned, f);
  v = v + 0x7fffu + ((v >> 16) & 1u);
  return (u16)(v >> 16);
}
static __device__ __forceinline__ float bf2f(u16 u) {
  unsigned v = ((unsigned)u) << 16;
  return __builtin_bit_cast(float, v);
}

#define GLOAD16(gp, lp)                                                        \
  __builtin_amdgcn_global_load_lds(                                            \
      (const __attribute__((address_space(1))) void*)(gp),                     \
      (__attribute__((address_space(3))) void*)(lp), 16, 0, 0)

// ------------- fused f32->bf16 convert for all 5 weight/act buffers ---------
__global__ void k_convert_all(const float* __restrict__ hs, const float* __restrict__ wq_a,
                              const float* __restrict__ wkv_a, const float* __restrict__ wqb,
                              const float* __restrict__ wkvb, const float* __restrict__ wo,
                              u16* __restrict__ hs_bf, u16* __restrict__ wqkva,
                              u16* __restrict__ wqb_bf, u16* __restrict__ wkvb_bf,
                              u16* __restrict__ wo_bf) {
  const long NQ = 4915200;
  long q = (long)blockIdx.x * blockDim.x + threadIdx.x;
  const long stride = (long)gridDim.x * blockDim.x;
  for (; q < NQ; q += stride) {
    const float* src;
    u16* dst;
    long li;
    bool zero = false;
    if (q < 1048576)        { src = hs;   dst = hs_bf;                      li = q; }
    else if (q < 1835008)   { src = wq_a; dst = wqkva;                      li = q - 1048576; }
    else if (q < 2162688)   { li = q - 1835008; src = wkv_a; dst = wqkva + (size_t)QLR * HID;
                              zero = (li >= 294912); }
    else if (q < 3342336)   { src = wqb;  dst = wqb_bf;                     li = q - 2162688; }
    else if (q < 3866624)   { src = wkvb; dst = wkvb_bf;                    li = q - 3342336; }
    else                    { src = wo;   dst = wo_bf;                      li = q - 3866624; }
    u16 o0 = 0, o1 = 0, o2 = 0, o3 = 0;
    if (!zero) {
      const float4 f = *(const float4*)(src + li * 4);
      o0 = f2bf(f.x); o1 = f2bf(f.y); o2 = f2bf(f.z); o3 = f2bf(f.w);
    }
    u16* d = dst + li * 4;
    d[0] = o0; d[1] = o1; d[2] = o2; d[3] = o3;
  }
}

// ---------------- fused row RMSNorm (y-dim selects q / kv config) ----------
__global__ void k_rmsnorm2(const float* __restrict__ qkva, const float* __restrict__ qw,
                           const float* __restrict__ kvw, u16* __restrict__ q_ln,
                           u16* __restrict__ kv_ln) {
  const int row = blockIdx.x;
  const int which = blockIdx.y;
  const int t = threadIdx.x;
  const int cols = which ? KVLR : QLR;
  const float inv_cols = which ? (1.0f / KVLR) : (1.0f / QLR);
  const float* x = qkva + (size_t)row * NKVA + (which ? QLR : 0);
  const float* w = which ? kvw : qw;
  u16* Y = (which ? kv_ln : q_ln) + (size_t)row * cols;
  float ss = 0.f;
  for (int i = t * 4; i < cols; i += 1024) {
    float4 v = *(const float4*)(x + i);
    ss += v.x * v.x + v.y * v.y + v.z * v.z + v.w * v.w;
  }
#pragma unroll
  for (int m = 1; m < 64; m <<= 1) ss += __shfl_xor(ss, m, 64);
  __shared__ float red[4];
  if ((t & 63) == 0) red[t >> 6] = ss;
  __syncthreads();
  float tot = red[0] + red[1] + red[2] + red[3];
  float r = rsqrtf(tot * inv_cols + 1e-6f);
  for (int i = t * 4; i < cols; i += 1024) {
    float4 v = *(const float4*)(x + i);
    float4 g = *(const float4*)(w + i);
    u16* y = Y + i;
    y[0] = f2bf(v.x * r * g.x);
    y[1] = f2bf(v.y * r * g.y);
    y[2] = f2bf(v.z * r * g.z);
    y[3] = f2bf(v.w * r * g.w);
  }
}

// ------------- NT GEMM 8-wave wide tile, NBUF-deep counted-vmcnt ------------
// BM=128, BN=WN*64; waves 2(row)x4(col). mode: 0 = f32 store, 1 = bf16 store.
template <int WN, int NBUF>
__global__ __launch_bounds__(512) void k_gemm_nt8(
    const u16* __restrict__ A, const u16* __restrict__ B, void* __restrict__ Cout,
    int M, int N, int K, int mode) {
  constexpr int BN = WN * 64;
  constexpr int NST = 2 + WN;  // gload instrs per STAGE8
  __shared__ __align__(16) u16 As[NBUF][128 * 64];
  __shared__ __align__(16) u16 Bs[NBUF][BN * 64];
  const int t = threadIdx.x;
  const int lane = t & 63;
  const int w = t >> 6, wr = w >> 2, wc = w & 3;
  const int lm = lane & 15, lg = lane >> 4;

  const int nwg = gridDim.x * gridDim.y;
  int bid = blockIdx.y * gridDim.x + blockIdx.x;
  if ((nwg & 7) == 0) bid = (bid & 7) * (nwg >> 3) + (bid >> 3);
  const int bm = bid % gridDim.y;
  const int bn = bid / gridDim.y;

  const u16* aT = A + (size_t)bm * 128 * K;
  const u16* bT = B + (size_t)bn * BN * K;

#define STAGE8(buf, kt_)                                                       \
  do {                                                                         \
    _Pragma("unroll") for (int i = 0; i < 2; ++i) {                            \
      const int g = t + i * 512, row = g >> 3, slot = (g & 7) ^ (row & 7);     \
      GLOAD16(aT + (size_t)row * K + slot * 8 + (kt_), (u16*)As[buf] + g * 8); \
    }                                                                          \
    _Pragma("unroll") for (int i = 0; i < WN; ++i) {                           \
      const int g = t + i * 512, row = g >> 3, slot = (g & 7) ^ (row & 7);     \
      GLOAD16(bT + (size_t)row * K + slot * 8 + (kt_), (u16*)Bs[buf] + g * 8); \
    }                                                                          \
  } while (0)

  f32x4 acc[4][WN] = {};
  const int nk = K >> 6;
#pragma unroll
  for (int b = 0; b < NBUF; ++b)
    if (b < nk) STAGE8(b, b << 6);
  int bt = 0;
  for (int kt = 0; kt < nk; ++kt) {
    const int rem = nk - 1 - kt;
    if constexpr (NBUF == 3) {
      if (rem >= 2)      asm volatile("s_waitcnt vmcnt(%0)" :: "i"(2 * NST) : "memory");
      else if (rem == 1) asm volatile("s_waitcnt vmcnt(%0)" :: "i"(NST) : "memory");
      else               asm volatile("s_waitcnt vmcnt(0)" ::: "memory");
    } else {
      if (rem >= 1)      asm volatile("s_waitcnt vmcnt(%0)" :: "i"(NST) : "memory");
      else               asm volatile("s_waitcnt vmcnt(0)" ::: "memory");
    }
    __builtin_amdgcn_s_barrier();
    __builtin_amdgcn_sched_barrier(0);
    bf16x8 af[2][4], bfr[2][WN];
#pragma unroll
    for (int kk = 0; kk < 2; ++kk) {
#pragma unroll
      for (int i = 0; i < 4; ++i) {
        const int row_ = wr * 64 + i * 16 + lm;
        af[kk][i] = *(const bf16x8*)(As[bt] + row_ * 64 +
                                     ((((kk << 2) | lg) ^ (row_ & 7)) << 3));
      }
#pragma unroll
      for (int j = 0; j < WN; ++j) {
        const int row_ = wc * (WN * 16) + j * 16 + lm;
        bfr[kk][j] = *(const bf16x8*)(Bs[bt] + row_ * 64 +
                                      ((((kk << 2) | lg) ^ (row_ & 7)) << 3));
      }
    }
    asm volatile("s_waitcnt lgkmcnt(0)" ::: "memory");
    __builtin_amdgcn_sched_barrier(0);
    __builtin_amdgcn_s_barrier();
    __builtin_amdgcn_sched_barrier(0);
    if (kt + NBUF < nk) STAGE8(bt, (kt + NBUF) << 6);  // same buf (mod NBUF)
    __builtin_amdgcn_s_setprio(1);
#pragma unroll
    for (int kk = 0; kk < 2; ++kk)
#pragma unroll
      for (int i = 0; i < 4; ++i)
#pragma unroll
        for (int j = 0; j < WN; ++j)
          acc[i][j] = __builtin_amdgcn_mfma_f32_16x16x32_bf16(af[kk][i], bfr[kk][j],
                                                              acc[i][j], 0, 0, 0);
    __builtin_amdgcn_s_setprio(0);
    bt = (bt == NBUF - 1) ? 0 : bt + 1;
  }
#undef STAGE8

  const int row0 = bm * 128 + wr * 64 + lg * 4;
  const int col0 = bn * BN + wc * (WN * 16) + lm;
  if (mode == 1) {
    u16* C = (u16*)Cout;
#pragma unroll
    for (int i = 0; i < 4; ++i)
#pragma unroll
      for (int r = 0; r < 4; ++r) {
        u16* crow = C + (size_t)(row0 + i * 16 + r) * N + col0;
#pragma unroll
        for (int j = 0; j < WN; ++j) crow[j * 16] = f2bf(acc[i][j][r]);
      }
  } else {
    float* C = (float*)Cout;
#pragma unroll
    for (int i = 0; i < 4; ++i)
#pragma unroll
      for (int r = 0; r < 4; ++r) {
        float* crow = C + (size_t)(row0 + i * 16 + r) * N + col0;
#pragma unroll
        for (int j = 0; j < WN; ++j) crow[j * 16] = acc[i][j][r];
      }
  }
}

// ---- fused assemble: qf (pre-scaled, exp2 domain) + kf + v_t[h][d][s] ------
__global__ __launch_bounds__(256) void k_mk_all(
    const u16* __restrict__ qfull, const u16* __restrict__ kvfull,
    const float* __restrict__ krot, int krot_stride,
    const float* __restrict__ cosb, const float* __restrict__ sinb,
    u16* __restrict__ qf, u16* __restrict__ kf, u16* __restrict__ vt) {
  __shared__ u16 vts[128][66];
  const int s0 = blockIdx.x * 64, h = blockIdx.y, t = threadIdx.x;
#pragma unroll
  for (int i = 0; i < 8; ++i) {
    const int g = t + i * 256, row = g >> 5, slot = g & 31;
    const u16* src = kvfull + (size_t)(s0 + row) * (NH * 256) + h * 256 + slot * 8;
    bf16x8 v = *(const bf16x8*)src;
    if (slot < 16) {
      *(bf16x8*)(kf + ((size_t)h * SEQ + s0 + row) * DQK + slot * 8) = v;
    } else {
      const int d = (slot - 16) * 8;
#pragma unroll
      for (int e = 0; e < 8; ++e) vts[d + e][row] = (u16)v[e];
    }
  }
#pragma unroll
  for (int i = 0; i < 8; ++i) {
    const int g = t + i * 256, row = g >> 5, c = g & 31;
    const size_t kb = (size_t)(s0 + row) * krot_stride + 2 * c;
    float a = krot[kb];
    float b = krot[kb + 1];
    float cc = cosb[(size_t)(s0 + row) * DR + c];
    float sn = sinb[(size_t)(s0 + row) * DR + c];
    u16* kd = kf + ((size_t)h * SEQ + s0 + row) * DQK;
    kd[DN + c] = f2bf(a * cc - b * sn);
    kd[DN + 32 + c] = f2bf(b * cc + a * sn);
  }
  __syncthreads();
#pragma unroll
  for (int i = 0; i < 4; ++i) {
    const int g = t + i * 256, d = g >> 3, slot = g & 7;
    bf16x8 v;
#pragma unroll
    for (int e = 0; e < 8; ++e) v[e] = (short)vts[d][slot * 8 + e];
    *(bf16x8*)(vt + ((size_t)h * DV + d) * SEQ + s0 + slot * 8) = v;
  }
#pragma unroll
  for (int i = 0; i < 4; ++i) {
    const int g = t + i * 256, row = g >> 4, vc = g & 15;
    const u16* src = qfull + (size_t)(s0 + row) * (NH * DQK) + h * DQK + vc * 8;
    bf16x8 v = *(const bf16x8*)src;
    bf16x8 o;
#pragma unroll
    for (int e = 0; e < 8; ++e) o[e] = (short)f2bf(bf2f((u16)v[e]) * SCL2);
    *(bf16x8*)(qf + ((size_t)h * SEQ + s0 + row) * DQK + vc * 8) = o;
  }
#pragma unroll
  for (int i = 0; i < 8; ++i) {
    const int g = t + i * 256, row = g >> 5, c = g & 31;
    const u16* src = qfull + (size_t)(s0 + row) * (NH * DQK) + h * DQK;
    float a = bf2f(src[DN + 2 * c]);
    float b = bf2f(src[DN + 2 * c + 1]);
    float cc = cosb[(size_t)(s0 + row) * DR + c];
    float sn = sinb[(size_t)(s0 + row) * DR + c];
    u16* qd = qf + ((size_t)h * SEQ + s0 + row) * DQK;
    qd[DN + c] = f2bf((a * cc - b * sn) * SCL2);
    qd[DN + 32 + c] = f2bf((b * cc + a * sn) * SCL2);
  }
}

// ---------------- flash attention v10: split-long-tiles, 768 blocks ---------
__global__ __launch_bounds__(256) void k_attn(
    const u16* __restrict__ qf, const u16* __restrict__ kf, const u16* __restrict__ vt,
    u16* __restrict__ attn_out, float* __restrict__ O_part, float* __restrict__ mlbuf) {
  __shared__ __align__(16) u16 Ks[2][32 * 192];
  __shared__ __align__(16) u16 Vs[2][128 * 32];
  __shared__ __align__(16) u16 p_lds[4][16][32];

  static const signed char TJ[24] = {15,15,7,14,14,13,13,6,12,12,11,11,5,
                                     10,10,9,9,4,8,8,3,2,1,0};
  static const signed char CK[24] = {0,1,2,0,1,0,1,2,0,1,0,1,2,
                                     0,1,0,1,2,0,1,2,2,2,2};

  const int t = threadIdx.x, lane = t & 63, w = t >> 6;
  const int lm = lane & 15, lg = lane >> 4;
  const int bid = blockIdx.x;
  const int x = bid & 7, rr = bid >> 3;   // rr in [0,96)
  const int hh = rr & 1, idx = rr >> 1;   // idx in [0,48)
  const int seg = idx & 1, slot = idx >> 1;
  const int tj = TJ[slot], ck = CK[slot];
  const int h = x * 2 + hh;               // 2 heads per XCD
  const int tile_row0 = seg * 1024 + tj * 64;
  const int k_begin = seg * 1024;
  const int n_all = 2 * tj + 2;
  const int kt_lo = (ck == 1) ? (tj + 1) : 0;
  const int kt_hi = (ck == 0) ? (tj + 1) : n_all;
  const int n_kt = kt_hi - kt_lo;         // >= 2 always

  const int lo_row = tile_row0 + w * 16;
  bf16x8 qfr[6];
  {
    const u16* qp = qf + ((size_t)h * SEQ + (lo_row + lm)) * DQK + lg * 8;
#pragma unroll
    for (int c = 0; c < 6; ++c) qfr[c] = *(const bf16x8*)(qp + c * 32);
  }
  int qrow[4];
#pragma unroll
  for (int r = 0; r < 4; ++r) qrow[r] = lo_row + lg * 4 + r;

  float m_r[4], l_loc[4];
#pragma unroll
  for (int r = 0; r < 4; ++r) { m_r[r] = -3.0e4f; l_loc[r] = 0.f; }
  f32x4 oacc[8] = {};
  bf16x8 pa, vv[8];

#define STAGEA(buf, kt_)                                                       \
  do {                                                                         \
    const int k0_ = k_begin + (kt_) * 32;                                      \
    _Pragma("unroll") for (int p = 0; p < 3; ++p) {                            \
      const int id = p * 256 + t;                                              \
      const int row = id / 24, colL = id - row * 24;                           \
      const u16* g = kf + ((size_t)h * SEQ + k0_ + row) * DQK +                \
                     ((colL ^ (row & 7)) * 8);                                 \
      GLOAD16(g, (u16*)Ks[buf] + id * 8);                                      \
    }                                                                          \
    _Pragma("unroll") for (int p = 0; p < 2; ++p) {                            \
      const int id = p * 256 + t;                                              \
      const int row = id >> 2, colL = id & 3;                                  \
      const u16* g = vt + ((size_t)h * DV + row) * SEQ + k0_ +                 \
                     ((colL ^ (row & 3)) * 8);                                 \
      GLOAD16(g, (u16*)Vs[buf] + id * 8);                                      \
    }                                                                          \
  } while (0)

#define COMPUTE1(buf, kt_)                                                     \
  do {                                                                         \
    const int k0_ = k_begin + (kt_) * 32;                                      \
    f32x4 sc[2] = {};                                                          \
    __builtin_amdgcn_s_setprio(1);                                             \
    _Pragma("unroll") for (int n0_ = 0; n0_ < 2; ++n0_)                        \
        _Pragma("unroll") for (int c_ = 0; c_ < 6; ++c_) {                     \
      const int row_ = n0_ * 16 + lm, cc_ = c_ * 4 + lg;                       \
      bf16x8 kfr = *(const bf16x8*)(Ks[buf] + row_ * 192 +                     \
                                    ((cc_ ^ (row_ & 7)) * 8));                 \
      sc[n0_] = __builtin_amdgcn_mfma_f32_16x16x32_bf16(qfr[c_], kfr,          \
                                                        sc[n0_], 0, 0, 0);     \
    }                                                                          \
    __builtin_amdgcn_s_setprio(0);                                             \
    _Pragma("unroll") for (int nd = 0; nd < 8; ++nd) {                         \
      const int row_ = nd * 16 + lm;                                           \
      vv[nd] = *(const bf16x8*)(Vs[buf] + row_ * 32 +                          \
                                ((lg ^ (row_ & 3)) * 8));                      \
    }                                                                          \
    float s0a[4], s1a[4];                                                      \
    float over = -1e30f;                                                       \
    if (lo_row >= k0_ + 31) {                                                  \
      _Pragma("unroll") for (int r = 0; r < 4; ++r) {                          \
        s0a[r] = sc[0][r];                                                     \
        s1a[r] = sc[1][r];                                                     \
        over = fmaxf(over, fmaxf(s0a[r], s1a[r]) - m_r[r]);                    \
      }                                                                        \
    } else {                                                                   \
      const int kc0 = k0_ + lm, kc1 = k0_ + 16 + lm;                           \
      _Pragma("unroll") for (int r = 0; r < 4; ++r) {                          \
        s0a[r] = (kc0 <= qrow[r]) ? sc[0][r] : -1e30f;                         \
        s1a[r] = (kc1 <= qrow[r]) ? sc[1][r] : -1e30f;                         \
        over = fmaxf(over, fmaxf(s0a[r], s1a[r]) - m_r[r]);                    \
      }                                                                        \
    }                                                                          \
    if (__any(over > THR2)) {                                                  \
      _Pragma("unroll") for (int r = 0; r < 4; ++r) {                          \
        float mx = fmaxf(s0a[r], s1a[r]);                                      \
        _Pragma("unroll") for (int md = 1; md < 16; md <<= 1)                  \
            mx = fmaxf(mx, __shfl_xor(mx, md, 64));                            \
        float mnew = fmaxf(m_r[r], mx);                                        \
        float alpha = exp2f(m_r[r] - mnew);                                    \
        m_r[r] = mnew;                                                         \
        l_loc[r] *= alpha;                                                     \
        _Pragma("unroll") for (int nd = 0; nd < 8; ++nd) oacc[nd][r] *= alpha; \
      }                                                                        \
    }                                                                          \
    _Pragma("unroll") for (int r = 0; r < 4; ++r) {                            \
      float p0 = exp2f(s0a[r] - m_r[r]);                                       \
      float p1 = exp2f(s1a[r] - m_r[r]);                                       \
      l_loc[r] += p0 + p1;                                                     \
      p_lds[w][lg * 4 + r][lm] = f2bf(p0);                                     \
      p_lds[w][lg * 4 + r][16 + lm] = f2bf(p1);                                \
    }                                                                          \
    asm volatile("s_waitcnt lgkmcnt(0)" ::: "memory");                         \
    __builtin_amdgcn_sched_barrier(0);                                         \
    pa = *(const bf16x8*)(&p_lds[w][lm][lg * 8]);                              \
  } while (0)

  STAGEA(0, kt_lo);
  STAGEA(1, kt_lo + 1);  // n_kt >= 2 always
  for (int i = 0; i < n_kt; ++i) {
    const int kt = kt_lo + i;
    if (i + 1 < n_kt) asm volatile("s_waitcnt vmcnt(5)" ::: "memory");
    else              asm volatile("s_waitcnt vmcnt(0)" ::: "memory");
    __builtin_amdgcn_s_barrier();
    __builtin_amdgcn_sched_barrier(0);
    COMPUTE1(i & 1, kt);
    asm volatile("s_waitcnt lgkmcnt(0)" ::: "memory");
    __builtin_amdgcn_sched_barrier(0);
    __builtin_amdgcn_s_barrier();
    __builtin_amdgcn_sched_barrier(0);
    if (i + 2 < n_kt) STAGEA(i & 1, kt + 2);
    __builtin_amdgcn_s_setprio(1);
#pragma unroll
    for (int nd = 0; nd < 8; ++nd)
      oacc[nd] = __builtin_amdgcn_mfma_f32_16x16x32_bf16(pa, vv[nd], oacc[nd], 0, 0, 0);
    __builtin_amdgcn_s_setprio(0);
  }
#undef STAGEA
#undef COMPUTE1

  float l_row[4];
#pragma unroll
  for (int r = 0; r < 4; ++r) {
    float lt = l_loc[r];
#pragma unroll
    for (int md = 1; md < 16; md <<= 1) lt += __shfl_xor(lt, md, 64);
    l_row[r] = lt;
  }

  if (ck == 2) {
#pragma unroll
    for (int r = 0; r < 4; ++r) {
      float inv = 1.0f / l_row[r];
#pragma unroll
      for (int nd = 0; nd < 8; ++nd)
        attn_out[(size_t)qrow[r] * (NH * DV) + h * DV + nd * 16 + lm] =
            f2bf(oacc[nd][r] * inv);
    }
  } else {
    const int part = (((tj - 8) * 2 + seg) * 16 + h) * 2 + ck;  // [0,512)
    float* op = O_part + (size_t)part * 8192;
#pragma unroll
    for (int r = 0; r < 4; ++r) {
      const int rw = w * 16 + lg * 4 + r;  // [0,64)
#pragma unroll
      for (int nd = 0; nd < 8; ++nd)
        op[rw * 128 + nd * 16 + lm] = oacc[nd][r];
      if (lm == 0) {
        mlbuf[part * 128 + rw] = m_r[r];
        mlbuf[part * 128 + 64 + rw] = l_row[r];
      }
    }
  }
}

// ---------------- merge 2 chunks per split tile -----------------------------
__global__ __launch_bounds__(256) void k_merge(const float* __restrict__ O_part,
                                               const float* __restrict__ mlbuf,
                                               u16* __restrict__ attn_out) {
  const int b = blockIdx.x;            // [0,256)
  const int h = b & 15, z = b >> 4;    // z in [0,16)
  const int tj = 8 + (z >> 1), seg = z & 1;
  const int p0 = (((tj - 8) * 2 + seg) * 16 + h) * 2;
  const int p1 = p0 + 1;
  const int t = threadIdx.x;
  const int row = t >> 2, cg = t & 3;

  const float m0 = mlbuf[p0 * 128 + row], l0 = mlbuf[p0 * 128 + 64 + row];
  const float m1 = mlbuf[p1 * 128 + row], l1 = mlbuf[p1 * 128 + 64 + row];
  const float M = fmaxf(m0, m1);
  const float w0 = exp2f(m0 - M), w1 = exp2f(m1 - M);
  const float inv = 1.0f / (w0 * l0 + w1 * l1);
  const float a0 = w0 * inv, a1 = w1 * inv;

  const int qrow = seg * 1024 + tj * 64 + row;
  const float* o0 = O_part + (size_t)p0 * 8192 + row * 128 + cg * 32;
  const float* o1 = O_part + (size_t)p1 * 8192 + row * 128 + cg * 32;
  u16* dst = attn_out + (size_t)qrow * (NH * DV) + h * DV + cg * 32;
#pragma unroll
  for (int e = 0; e < 32; e += 4) {
    const float4 u = *(const float4*)(o0 + e);
    const float4 v = *(const float4*)(o1 + e);
    dst[e]     = f2bf(a0 * u.x + a1 * v.x);
    dst[e + 1] = f2bf(a0 * u.y + a1 * v.y);
    dst[e + 2] = f2bf(a0 * u.z + a1 * v.z);
    dst[e + 3] = f2bf(a0 * u.w + a1 * v.w);
  }
}

extern "C" void kernel_launch(void* const* d_in, const int* in_sizes, int n_in,
                              void* d_out, int out_size, void* d_ws, size_t ws_size,
                              hipStream_t stream) {
  const float* hs = (const float*)d_in[0];
  const float* cosb = (const float*)d_in[1];
  const float* sinb = (const float*)d_in[2];
  const float* wq_a = (const float*)d_in[3];
  const float* q_a_ln_w = (const float*)d_in[4];
  const float* wq_b = (const float*)d_in[5];
  const float* wkv_a = (const float*)d_in[6];
  const float* kv_a_ln_w = (const float*)d_in[7];
  const float* wkv_b = (const float*)d_in[8];
  const float* wo = (const float*)d_in[9];

  char* ws = (char*)d_ws;
  size_t off = 0;
  auto take = [&](size_t bytes) {
    size_t o = off;
    off += (bytes + 255) & ~(size_t)255;
    return o;
  };
  u16* hs_bf = (u16*)(ws + take((size_t)SEQ * HID * 2));
  u16* wqkva = (u16*)(ws + take((size_t)NKVA * HID * 2));
  u16* wqb = (u16*)(ws + take((size_t)(NH * DQK) * QLR * 2));
  u16* wkvb = (u16*)(ws + take((size_t)(NH * 256) * KVLR * 2));
  u16* wo_bf = (u16*)(ws + take((size_t)HID * (NH * DV) * 2));
  float* qkva = (float*)(ws + take((size_t)SEQ * NKVA * 4));
  u16* q_ln = (u16*)(ws + take((size_t)SEQ * QLR * 2));
  u16* kv_ln = (u16*)(ws + take((size_t)SEQ * KVLR * 2));
  u16* qfull = (u16*)(ws + take((size_t)SEQ * NH * DQK * 2));
  u16* kvfull = (u16*)(ws + take((size_t)SEQ * NH * 256 * 2));
  u16* qf = (u16*)(ws + take((size_t)NH * SEQ * DQK * 2));
  u16* kf = (u16*)(ws + take((size_t)NH * SEQ * DQK * 2));
  u16* vt = (u16*)(ws + take((size_t)NH * DV * SEQ * 2));
  u16* attn = (u16*)(ws + take((size_t)SEQ * NH * DV * 2));
  if (off > ws_size) return;
  // split-K attn partials aliased onto buffers dead after k_mk_all:
  float* O_part = (float*)kvfull;   // 512 * 8192 * 4B = 16.78 MB (== kvfull)
  float* mlbuf = (float*)qfull;     // 512 * 128 * 4B = 256 KB (<= qfull)

  k_convert_all<<<2048, 256, 0, stream>>>(hs, wq_a, wkv_a, wq_b, wkv_b, wo,
                                          hs_bf, wqkva, wqb, wkvb, wo_bf);

  // g1: 8-wave WN=2, 2-buffer (64 KB -> 2 blocks/CU), 272 blocks co-resident
  dim3 g1(NKVA / 128, SEQ / 128);
  k_gemm_nt8<2, 2><<<g1, 512, 0, stream>>>(hs_bf, wqkva, qkva, SEQ, NKVA, HID, 0);

  k_rmsnorm2<<<dim3(SEQ, 2), 256, 0, stream>>>(qkva, q_a_ln_w, kv_a_ln_w, q_ln, kv_ln);

  dim3 g2(NH * DQK / 192, SEQ / 128);
  k_gemm_nt8<3, 2><<<g2, 512, 0, stream>>>(q_ln, wqb, qfull, SEQ, NH * DQK, QLR, 1);
  dim3 g3(NH * 256 / 256, SEQ / 128);
  k_gemm_nt8<4, 2><<<g3, 512, 0, stream>>>(kv_ln, wkvb, kvfull, SEQ, NH * 256, KVLR, 1);

  k_mk_all<<<dim3(SEQ / 64, NH), 256, 0, stream>>>(qfull, kvfull, qkva + (QLR + KVLR),
                                                   NKVA, cosb, sinb, qf, kf, vt);

  k_attn<<<768, 256, 0, stream>>>(qf, kf, vt, attn, O_part, mlbuf);
  k_merge<<<256, 256, 0, stream>>>(O_part, mlbuf, attn);

  // g4: 8-wave WN=2, 2-buffer, 256 blocks, f32 out
  dim3 g4(HID / 128, SEQ / 128);
  k_gemm_nt8<2, 2><<<g4, 512, 0, stream>>>(attn, wo_bf, d_out, SEQ, HID, NH * DV, 0);
}